// Round 2
// baseline (1928.794 us; speedup 1.0000x reference)
//
#include <hip/hip_runtime.h>
#include <cmath>

#define B_DIM 8192
#define M_DIM 512
#define N_DIM 2048
#define INROW 4608   // M + 2N
#define OUTROW 8704  // INROW + 2N
#define RANK_IDX 1945  // numpy 'nearest': (2047)*0.95 = 1944.65 -> 1945

// res[b][m] (f64) lives aliased in out[:, 0:1024] of row b (scratch until
// finalize overwrites with the input copy). Row base b*OUTROW*4 bytes is
// 16B-aligned (8704*4 = 34816 = 16*2176).
__device__ __forceinline__ double* res_row(float* out, int b) {
  return (double*)(out + (long long)b * OUTROW);
}
__device__ __forceinline__ const double* res_row_c(const float* out, int b) {
  return (const double*)(out + (long long)b * OUTROW);
}

// ---------------------------------------------------------------------------
// Kernel 1: compute gx in f64, store hi -> out[:, 4608:6656], lo -> out[:, 6656:8704]
// ---------------------------------------------------------------------------
__global__ __launch_bounds__(256) void prep_kernel(const float* __restrict__ in,
                                                   float* __restrict__ out) {
  const long long stride = (long long)gridDim.x * blockDim.x;
  const long long t0 = (long long)blockIdx.x * blockDim.x + threadIdx.x;

  const long long ngx = (long long)B_DIM * N_DIM;
  for (long long i = t0; i < ngx; i += stride) {
    long long b = i >> 11;
    int n = (int)(i & 2047);
    double xk = (double)in[b * INROW + (M_DIM + N_DIM) + n];
    double gx = (1.0 + 0.5 * exp(-fabs(xk))) * xk;
    float hi = (float)gx;
    float lo = (float)(gx - (double)hi);
    out[b * OUTROW + INROW + n] = hi;
    out[b * OUTROW + INROW + N_DIM + n] = lo;
  }
}

// ---------------------------------------------------------------------------
// Kernel 2: res[b][m] = y[b][m] - sum_n gx[b][n] * A[m][n]   (f64 accumulate)
// ---------------------------------------------------------------------------
__global__ __launch_bounds__(256) void gemm1_kernel(const float* __restrict__ in,
                                                    float* __restrict__ out,
                                                    const float* __restrict__ A) {
  __shared__ double As[64][17];
  __shared__ float Bs[16][68];
  const int tid = threadIdx.x;
  const int tx = tid & 15, ty = tid >> 4;
  const int m0 = blockIdx.x * 64;   // over M=512  (8 blocks)
  const int b0 = blockIdx.y * 64;   // over B=8192 (128 blocks)
  const int lr = tid >> 2;          // 0..63
  const int lk = (tid & 3) << 2;    // 0,4,8,12
  double acc[4][4] = {};

  for (int k0 = 0; k0 < N_DIM; k0 += 16) {
    const long long rowoff = (long long)(b0 + lr) * OUTROW;
    float4 h = *(const float4*)&out[rowoff + INROW + k0 + lk];
    float4 l = *(const float4*)&out[rowoff + INROW + N_DIM + k0 + lk];
    As[lr][lk + 0] = (double)h.x + (double)l.x;
    As[lr][lk + 1] = (double)h.y + (double)l.y;
    As[lr][lk + 2] = (double)h.z + (double)l.z;
    As[lr][lk + 3] = (double)h.w + (double)l.w;
    // Bs[k][m] = A[(m0+m)*N + k0+k]
    float4 av = *(const float4*)&A[(long long)(m0 + lr) * N_DIM + k0 + lk];
    Bs[lk + 0][lr] = av.x;
    Bs[lk + 1][lr] = av.y;
    Bs[lk + 2][lr] = av.z;
    Bs[lk + 3][lr] = av.w;
    __syncthreads();
#pragma unroll
    for (int kk = 0; kk < 16; ++kk) {
      double a[4], w[4];
#pragma unroll
      for (int i = 0; i < 4; ++i) a[i] = As[ty * 4 + i][kk];
#pragma unroll
      for (int j = 0; j < 4; ++j) w[j] = (double)Bs[kk][tx * 4 + j];
#pragma unroll
      for (int i = 0; i < 4; ++i)
#pragma unroll
        for (int j = 0; j < 4; ++j) acc[i][j] = fma(a[i], w[j], acc[i][j]);
    }
    __syncthreads();
  }

#pragma unroll
  for (int i = 0; i < 4; ++i) {
    const int bb = b0 + ty * 4 + i;
#pragma unroll
    for (int j = 0; j < 4; ++j) {
      const int mm = m0 + tx * 4 + j;
      double y = (double)in[(long long)bb * INROW + mm];
      res_row(out, bb)[mm] = y - acc[i][j];
    }
  }
}

// ---------------------------------------------------------------------------
// Kernel 3: zk[b][n] = gx[b][n] + 0.9 * sum_m res[b][m] * W[m][n]  (f64)
// zk hi -> out[:, 6656:8704], lo -> out[:, 4608:6656] (overwrites gx scratch)
// ---------------------------------------------------------------------------
__global__ __launch_bounds__(256) void gemm2_kernel(const float* __restrict__ W,
                                                    float* __restrict__ out) {
  __shared__ double As[64][17];
  __shared__ float Bs[16][68];
  const int tid = threadIdx.x;
  const int tx = tid & 15, ty = tid >> 4;
  const int n0 = blockIdx.x * 64;   // over N=2048 (32 blocks)
  const int b0 = blockIdx.y * 64;   // over B     (128 blocks)
  const int lr = tid >> 2;
  const int lk = (tid & 3) << 2;
  double acc[4][4] = {};

  for (int k0 = 0; k0 < M_DIM; k0 += 16) {
    const double* rp = res_row_c(out, b0 + lr) + k0 + lk;
    double2 r01 = *(const double2*)rp;
    double2 r23 = *(const double2*)(rp + 2);
    As[lr][lk + 0] = r01.x;
    As[lr][lk + 1] = r01.y;
    As[lr][lk + 2] = r23.x;
    As[lr][lk + 3] = r23.y;
    const int wk = tid >> 4;          // 0..15
    const int wn = (tid & 15) << 2;   // 0..60
    float4 wv = *(const float4*)&W[(long long)(k0 + wk) * N_DIM + n0 + wn];
    Bs[wk][wn + 0] = wv.x;
    Bs[wk][wn + 1] = wv.y;
    Bs[wk][wn + 2] = wv.z;
    Bs[wk][wn + 3] = wv.w;
    __syncthreads();
#pragma unroll
    for (int kk = 0; kk < 16; ++kk) {
      double a[4], w[4];
#pragma unroll
      for (int i = 0; i < 4; ++i) a[i] = As[ty * 4 + i][kk];
#pragma unroll
      for (int j = 0; j < 4; ++j) w[j] = (double)Bs[kk][tx * 4 + j];
#pragma unroll
      for (int i = 0; i < 4; ++i)
#pragma unroll
        for (int j = 0; j < 4; ++j) acc[i][j] = fma(a[i], w[j], acc[i][j]);
    }
    __syncthreads();
  }

#pragma unroll
  for (int i = 0; i < 4; ++i) {
    const int bb = b0 + ty * 4 + i;
    const long long base = (long long)bb * OUTROW;
    const int nn = n0 + tx * 4;
    float4 h = *(const float4*)&out[base + INROW + nn];           // gx hi
    float4 l = *(const float4*)&out[base + INROW + N_DIM + nn];   // gx lo
    double g0 = (double)h.x + (double)l.x;
    double g1 = (double)h.y + (double)l.y;
    double g2 = (double)h.z + (double)l.z;
    double g3 = (double)h.w + (double)l.w;
    double z0 = g0 + 0.9 * acc[i][0];
    double z1 = g1 + 0.9 * acc[i][1];
    double z2 = g2 + 0.9 * acc[i][2];
    double z3 = g3 + 0.9 * acc[i][3];
    float4 zh, zl;
    zh.x = (float)z0; zl.x = (float)(z0 - (double)zh.x);
    zh.y = (float)z1; zl.y = (float)(z1 - (double)zh.y);
    zh.z = (float)z2; zl.z = (float)(z2 - (double)zh.z);
    zh.w = (float)z3; zl.w = (float)(z3 - (double)zh.w);
    *(float4*)&out[base + INROW + N_DIM + nn] = zh;
    *(float4*)&out[base + INROW + nn] = zl;
  }
}

// ---------------------------------------------------------------------------
// Kernel 4: per-row percentile (bitonic sort of |zk| f64 bits, rank 1945),
// shrink + mixing, final cindex/output, and the inputs->out[:, :4608] copy
// (which overwrites the res scratch).
// ---------------------------------------------------------------------------
__global__ __launch_bounds__(256) void finalize_kernel(const float* __restrict__ in,
                                                       float* __restrict__ out) {
  __shared__ double zs[2048];
  __shared__ unsigned long long ks[2048];
  const int b = blockIdx.x;
  const int tid = threadIdx.x;
  const long long base = (long long)b * OUTROW;

  for (int i = tid; i < 2048; i += 256) {
    double z = (double)out[base + INROW + N_DIM + i] + (double)out[base + INROW + i];
    zs[i] = z;
    ks[i] = __double_as_longlong(fabs(z));  // nonneg doubles: bit order == value order
  }

  for (int k = 2; k <= 2048; k <<= 1) {
    for (int j = k >> 1; j > 0; j >>= 1) {
      __syncthreads();
      for (int i = tid; i < 2048; i += 256) {
        int ixj = i ^ j;
        if (ixj > i) {
          unsigned long long a = ks[i], c = ks[ixj];
          bool up = ((i & k) == 0);
          if ((a > c) == up) { ks[i] = c; ks[ixj] = a; }
        }
      }
    }
  }
  __syncthreads();

  const double thres = __longlong_as_double((long long)ks[RANK_IDX]);

  for (int i = tid; i < 2048; i += 256) {
    double z = zs[i];
    double az = fabs(z);
    bool ind = (az > 0.1) && (az > thres);
    double xk = (double)in[(long long)b * INROW + (M_DIM + N_DIM) + i];
    double cprev = (double)in[(long long)b * INROW + M_DIM + i];
    double sgn = (z > 0.0) ? 1.0 : ((z < 0.0) ? -1.0 : 0.0);
    double soft = sgn * fmax(az - 0.1, 0.0);
    double xkt = ind ? z : soft;
    double p1 = 1.0 / (fabs(xkt - xk) + 0.1);
    double p2 = 0.1 * cprev;
    double g = 1.0 - 0.5 * p1 * p2;
    double ov = g * xkt + (1.0 - g) * xk;
    out[base + INROW + i] = ind ? 0.0f : 1.0f;
    out[base + INROW + N_DIM + i] = (float)ov;
  }

  // input copy last — overwrites the f64 res scratch in out[:, 0:1024]
  const float4* in4 = (const float4*)(in + (long long)b * INROW);
  float4* out4 = (float4*)(out + base);
  for (int i = tid; i < INROW / 4; i += 256) out4[i] = in4[i];
}

extern "C" void kernel_launch(void* const* d_in, const int* in_sizes, int n_in,
                              void* d_out, int out_size, void* d_ws, size_t ws_size,
                              hipStream_t stream) {
  const float* in = (const float*)d_in[0];
  const float* A = (const float*)d_in[1];
  const float* W = (const float*)d_in[2];
  float* out = (float*)d_out;
  (void)d_ws; (void)ws_size;

  prep_kernel<<<1024, 256, 0, stream>>>(in, out);
  gemm1_kernel<<<dim3(M_DIM / 64, B_DIM / 64), 256, 0, stream>>>(in, out, A);
  gemm2_kernel<<<dim3(N_DIM / 64, B_DIM / 64), 256, 0, stream>>>(W, out);
  finalize_kernel<<<B_DIM, 256, 0, stream>>>(in, out);
}